// Round 16
// baseline (278.995 us; speedup 1.0000x reference)
//
#include <hip/hip_runtime.h>
#include <stdint.h>

// VectorQuantize on MI355X (gfx950) — bf16x3 MFMA distance-GEMM + argmin.
// Round 16: m201-style 8-phase schedule. BM=256 x BN=256, BK=32, 8 waves
// (4Mx2N, wave tile 64x128, acc[4][8]). Per K-step 8 phases: {2 pinned B
// ds_reads + 1 gll(next step) -> barrier -> lgkmcnt(0) -> 12 MFMA -> barrier}.
// A-frags pinned at phase 0 and held. Best/bidx live in LDS (frees regs).
// d_out: [0..N*DIM) quantized (fp32), [N*DIM..+N) ind (fp32), loss, perplexity.

#define N_VEC 16384
#define M_CODES 8192
#define DIM 256
#define BETA 0.25f

#define NSLICE 4
#define SLICE_CODES 2048
#define BM 256
#define BN 256
#define NPART 4                   // one partial per slice

#define BUF_BYTES 65536           // Xh 16K | Xl 16K | Eh 16K | El 16K
#define E2_OFF (2 * BUF_BYTES)    // 131072
#define BEST_OFF (E2_OFF + 8192)  // 139264 (512 x u64)
#define LDS_TOTAL (BEST_OFF + 4096)  // 143360 = 140 KiB
#define NSTEPS 64                 // 8 ct x 8 kc

typedef __attribute__((ext_vector_type(4))) float f32x4;
typedef __attribute__((ext_vector_type(4))) int i32x4;
typedef __attribute__((ext_vector_type(8))) __bf16 bf16x8;

__device__ __forceinline__ void gll16(const void* g, const void* lds_p) {
    __builtin_amdgcn_global_load_lds(
        (const __attribute__((address_space(1))) uint32_t*)(uintptr_t)g,
        (__attribute__((address_space(3))) uint32_t*)(uint32_t)(uintptr_t)lds_p,
        16, 0, 0);
}
#define SB0() __builtin_amdgcn_sched_barrier(0)
#define DSR(DST, ADDR, OFF) \
    asm volatile("ds_read_b128 %0, %1 offset:" #OFF : "=v"(DST) : "v"(ADDR))
#define LGKM(N) asm volatile("s_waitcnt lgkmcnt(" #N ")" ::: "memory")

__device__ __forceinline__ ushort f2bf(float f) {
    uint32_t u = __float_as_uint(f);
    return (ushort)((u + 0x7FFFu + ((u >> 16) & 1u)) >> 16);  // RNE
}
__device__ __forceinline__ float bf2f(ushort h) {
    return __uint_as_float(((uint32_t)h) << 16);
}

// ---- fused: split fp32 -> bf16 hi/lo for x and e, e2, zero counts/loss ----
__global__ __launch_bounds__(256) void prep_kernel(
    const float* __restrict__ x, const float* __restrict__ emb,
    ushort* __restrict__ xh, ushort* __restrict__ xl,
    ushort* __restrict__ eh, ushort* __restrict__ el,
    float* __restrict__ e2, unsigned* __restrict__ counts,
    float* __restrict__ loss_acc) {
    if (blockIdx.x < 8) {
        int4 z = {0, 0, 0, 0};
        ((int4*)counts)[blockIdx.x * 256 + threadIdx.x] = z;
        if (blockIdx.x == 0 && threadIdx.x == 0) *loss_acc = 0.0f;
    }
    const int wave = threadIdx.x >> 6;
    const int lane = threadIdx.x & 63;
    const int row = blockIdx.x * 4 + wave;

    const float* src;
    ushort* ph;
    ushort* pl;
    bool is_e;
    int er = row - N_VEC;
    if (row < N_VEC) {
        src = x + (size_t)row * DIM;
        ph = xh + (size_t)row * DIM;
        pl = xl + (size_t)row * DIM;
        is_e = false;
    } else {
        src = emb + (size_t)er * DIM;
        ph = eh + (size_t)er * DIM;
        pl = el + (size_t)er * DIM;
        is_e = true;
    }
    float4 v = *(const float4*)(src + lane * 4);
    ushort h0 = f2bf(v.x), h1 = f2bf(v.y), h2 = f2bf(v.z), h3 = f2bf(v.w);
    ushort l0 = f2bf(v.x - bf2f(h0)), l1 = f2bf(v.y - bf2f(h1));
    ushort l2 = f2bf(v.z - bf2f(h2)), l3 = f2bf(v.w - bf2f(h3));
    *(ushort4*)(ph + lane * 4) = make_ushort4(h0, h1, h2, h3);
    *(ushort4*)(pl + lane * 4) = make_ushort4(l0, l1, l2, l3);
    if (is_e) {
        float s = v.x * v.x + v.y * v.y + v.z * v.z + v.w * v.w;
        #pragma unroll
        for (int off = 32; off; off >>= 1) s += __shfl_xor(s, off);
        if (lane == 0) e2[er] = s;
    }
}

// ------ main: bf16x3 MFMA distance GEMM, 8-phase schedule, argmin ----
__global__ __launch_bounds__(512, 1) void vq_mfma_kernel(
    const ushort* __restrict__ xh, const ushort* __restrict__ xl,
    const ushort* __restrict__ eh, const ushort* __restrict__ el,
    const float* __restrict__ e2g, unsigned long long* __restrict__ partials) {
    extern __shared__ char lds[];

    const int t = threadIdx.x;
    const int lane = t & 63;
    const int wv = t >> 6;          // 0..7
    const int lane15 = lane & 15;
    const int l16 = lane >> 4;      // 0..3

    // rt-major mapping: XCD = bid%8 = rt%8 -> slice-siblings co-XCD
    const int rt = blockIdx.x & 63;
    const int slice = blockIdx.x >> 6;   // 0..3
    const int row0 = rt * BM;
    const int cslice0 = slice * SLICE_CODES;

    const int wr0 = (wv & 3) * 64;   // wave row group (fi 0..3 -> +16 each)
    const int wch = wv >> 2;         // wave col half: 128 codes (fj 0..7)

    // ---- fragment LDS byte bases (swizzle term is fi/fj-independent)
    const int swz = ((l16 ^ (lane15 >> 1)) & 3) << 4;
    const int byteA0 = (wr0 + lane15) * 64 + swz;
    const int byteB0 = (wch * 128 + lane15) * 64 + swz;

    // ---- staging: linear LDS dest, inverse-swizzled global source
    const int s0 = wv * 128 + lane;
    const int s1 = s0 + 64;
    const int r0s = s0 >> 2, r1s = s1 >> 2;
    const int c0s = ((s0 & 3) ^ ((s0 >> 3) & 3)) << 3;
    const int c1s = ((s1 & 3) ^ ((s1 >> 3) & 3)) << 3;

    const ushort* pxh_a = xh + (size_t)(row0 + r0s) * DIM + c0s;
    const ushort* pxh_b = xh + (size_t)(row0 + r1s) * DIM + c1s;
    const ushort* pxl_a = xl + (size_t)(row0 + r0s) * DIM + c0s;
    const ushort* pxl_b = xl + (size_t)(row0 + r1s) * DIM + c1s;
    const ushort* peh_a = eh + (size_t)(cslice0 + r0s) * DIM + c0s;
    const ushort* peh_b = eh + (size_t)(cslice0 + r1s) * DIM + c1s;
    const ushort* pel_a = el + (size_t)(cslice0 + r0s) * DIM + c0s;
    const ushort* pel_b = el + (size_t)(cslice0 + r1s) * DIM + c1s;

    float* e2s = (float*)(lds + E2_OFF);
    unsigned long long* bestU = (unsigned long long*)(lds + BEST_OFF);

    // preload e2 slice (2048 f32) + init best table; sync before ring starts
    #pragma unroll
    for (int i = 0; i < 4; ++i) e2s[i * 512 + t] = e2g[cslice0 + i * 512 + t];
    bestU[t] = ~0ull;
    __syncthreads();

    f32x4 acc[4][8];
    #pragma unroll
    for (int fi = 0; fi < 4; ++fi)
        #pragma unroll
        for (int fj = 0; fj < 8; ++fj) acc[fi][fj] = (f32x4){0.f, 0.f, 0.f, 0.f};

#define BURST(P) do {                                                        \
    bf16x8 BH_ = __builtin_bit_cast(bf16x8, bh_);                            \
    bf16x8 BL_ = __builtin_bit_cast(bf16x8, bl_);                            \
    _Pragma("unroll") for (int fi_ = 0; fi_ < 4; ++fi_)                      \
        acc[fi_][P] = __builtin_amdgcn_mfma_f32_16x16x32_bf16(               \
            __builtin_bit_cast(bf16x8, Ah[fi_]), BH_, acc[fi_][P], 0, 0, 0); \
    _Pragma("unroll") for (int fi_ = 0; fi_ < 4; ++fi_)                      \
        acc[fi_][P] = __builtin_amdgcn_mfma_f32_16x16x32_bf16(               \
            __builtin_bit_cast(bf16x8, Ah[fi_]), BL_, acc[fi_][P], 0, 0, 0); \
    _Pragma("unroll") for (int fi_ = 0; fi_ < 4; ++fi_)                      \
        acc[fi_][P] = __builtin_amdgcn_mfma_f32_16x16x32_bf16(               \
            __builtin_bit_cast(bf16x8, Al[fi_]), BH_, acc[fi_][P], 0, 0, 0); \
} while (0)

#define PHASE(P, OH, OL, ...) do {                                           \
    DSR(bh_, vB, OH); DSR(bl_, vB, OL);                                      \
    if (sn < NSTEPS) { __VA_ARGS__; }                                        \
    __builtin_amdgcn_s_barrier();                                            \
    LGKM(0); SB0();                                                          \
    __builtin_amdgcn_s_setprio(1);                                           \
    BURST(P);                                                                \
    __builtin_amdgcn_s_setprio(0);                                           \
    __builtin_amdgcn_s_barrier();                                            \
} while (0)

    // prologue: stage step 0 (8 gll) into buffer 0
    {
        char* b = lds + wv * 2048;
        gll16(pxh_a, b);
        gll16(pxh_b, b + 1024);
        gll16(pxl_a, b + 16384);
        gll16(pxl_b, b + 16384 + 1024);
        gll16(peh_a, b + 32768);
        gll16(peh_b, b + 32768 + 1024);
        gll16(pel_a, b + 49152);
        gll16(pel_b, b + 49152 + 1024);
        SB0();
    }

    for (int s = 0; s < NSTEPS; ++s) {
        // top: step-s loads (issued a full step ago) are the only ones in FIFO
        asm volatile("s_waitcnt vmcnt(0)" ::: "memory");
        __builtin_amdgcn_s_barrier();
        SB0();

        const int sn = s + 1;
        const int xo = (sn & 7) * 32;
        const size_t eo = ((size_t)(sn >> 3) << 16) + (sn & 7) * 32;
        char* wb = lds + (sn & 1) * BUF_BYTES + wv * 2048;
        const char* rb = lds + (s & 1) * BUF_BYTES;
        const uint32_t vA = (uint32_t)(uintptr_t)rb + (uint32_t)byteA0;
        const uint32_t vB = (uint32_t)(uintptr_t)rb + 32768u + (uint32_t)byteB0;

        i32x4 Ah[4], Al[4], bh_, bl_;

        // phase 0: A frags + B(0); gll #0
        DSR(Ah[0], vA, 0);     DSR(Ah[1], vA, 1024);
        DSR(Ah[2], vA, 2048);  DSR(Ah[3], vA, 3072);
        DSR(Al[0], vA, 16384); DSR(Al[1], vA, 17408);
        DSR(Al[2], vA, 18432); DSR(Al[3], vA, 19456);
        DSR(bh_, vB, 0);       DSR(bl_, vB, 16384);
        if (sn < NSTEPS) { gll16(pxh_a + xo, wb); }
        LGKM(0); SB0();
        __builtin_amdgcn_s_setprio(1);
        BURST(0);
        __builtin_amdgcn_s_setprio(0);
        __builtin_amdgcn_s_barrier();

        PHASE(1, 1024, 17408, gll16(pxh_b + xo, wb + 1024));
        PHASE(2, 2048, 18432, gll16(pxl_a + xo, wb + 16384));
        PHASE(3, 3072, 19456, gll16(pxl_b + xo, wb + 16384 + 1024));
        PHASE(4, 4096, 20480, gll16(peh_a + eo, wb + 32768));
        PHASE(5, 5120, 21504, gll16(peh_b + eo, wb + 32768 + 1024));
        PHASE(6, 6144, 22528, gll16(pel_a + eo, wb + 49152));
        PHASE(7, 7168, 23552, gll16(pel_b + eo, wb + 49152 + 1024));

        if ((s & 7) == 7) {
            // ct epilogue: score = e2[c] - 2*dot; C/D col=lane15, row=l16*4+r
            const int ct = s >> 3;
            float e2v[8];
            #pragma unroll
            for (int fj = 0; fj < 8; ++fj)
                e2v[fj] = e2s[ct * 256 + wch * 128 + fj * 16 + lane15];
            const int cb = cslice0 + ct * 256 + wch * 128 + lane15;
            #pragma unroll
            for (int fi = 0; fi < 4; ++fi)
                #pragma unroll
                for (int r = 0; r < 4; ++r) {
                    float m = e2v[0] - 2.0f * acc[fi][0][r];
                    int c = cb;
                    #pragma unroll
                    for (int fj = 1; fj < 8; ++fj) {
                        float sc = e2v[fj] - 2.0f * acc[fi][fj][r];
                        if (sc < m) { m = sc; c = cb + fj * 16; }
                    }
                    #pragma unroll
                    for (int off = 1; off < 16; off <<= 1) {
                        float v2 = __shfl_xor(m, off);
                        int c2 = __shfl_xor(c, off);
                        if (v2 < m || (v2 == m && c2 < c)) { m = v2; c = c2; }
                    }
                    if (lane15 == 0) {
                        int rowL = wr0 + fi * 16 + l16 * 4 + r;
                        uint32_t u = __float_as_uint(m);
                        uint32_t ord =
                            (u & 0x80000000u) ? ~u : (u | 0x80000000u);
                        unsigned long long pk =
                            ((unsigned long long)ord << 32) | (unsigned)c;
                        unsigned long long* e = &bestU[wch * 256 + rowL];
                        if (pk < *e) *e = pk;
                    }
                }
            #pragma unroll
            for (int fi = 0; fi < 4; ++fi)
                #pragma unroll
                for (int fj = 0; fj < 8; ++fj)
                    acc[fi][fj] = (f32x4){0.f, 0.f, 0.f, 0.f};
        }
    }
#undef PHASE
#undef BURST

    // merge the two col-half tables; one partial per row per block
    __syncthreads();
    if (t < 256) {
        unsigned long long m = bestU[t];
        unsigned long long m2 = bestU[256 + t];
        if (m2 < m) m = m2;
        partials[(size_t)slice * N_VEC + row0 + t] = m;
    }
}

// ---------------- fused: per-row min over partials + gather + loss + counts
__global__ __launch_bounds__(256) void finish_kernel(
    const float* __restrict__ x, const float* __restrict__ emb,
    const unsigned long long* __restrict__ partials,
    float* __restrict__ out_ind, float* __restrict__ out_q,
    unsigned* __restrict__ counts, float* __restrict__ loss_acc) {
    __shared__ float partial[4];
    const int wave = threadIdx.x >> 6;
    const int lane = threadIdx.x & 63;
    const int row = blockIdx.x * 4 + wave;

    unsigned long long m = ~0ull;
    if (lane < NPART) m = partials[(size_t)lane * N_VEC + row];
    #pragma unroll
    for (int off = 1; off < NPART; off <<= 1) {
        unsigned long long v = __shfl_xor(m, off);
        if (v < m) m = v;
    }
    m = __shfl(m, 0);
    const int ix = (int)(unsigned)(m & 0xFFFFFFFFull);

    float4 q = *(const float4*)(emb + (size_t)ix * DIM + lane * 4);
    float4 xv = *(const float4*)(x + (size_t)row * DIM + lane * 4);
    *(float4*)(out_q + (size_t)row * DIM + lane * 4) = q;
    float dx = q.x - xv.x, dy = q.y - xv.y, dz = q.z - xv.z, dw = q.w - xv.w;
    float s = dx * dx + dy * dy + dz * dz + dw * dw;
    #pragma unroll
    for (int off = 32; off; off >>= 1) s += __shfl_xor(s, off);
    if (lane == 0) {
        out_ind[row] = (float)ix;
        atomicAdd(&counts[ix], 1u);
        partial[wave] = s;
    }
    __syncthreads();
    if (threadIdx.x == 0)
        atomicAdd(loss_acc, partial[0] + partial[1] + partial[2] + partial[3]);
}

// -------------------------------------------------- entropy / loss finalize
__global__ __launch_bounds__(256) void finalize_kernel(
    const unsigned* __restrict__ counts, const float* __restrict__ loss_acc,
    float* __restrict__ out_scalars) {
    __shared__ float red[256];
    float h = 0.0f;
    for (int c = threadIdx.x; c < M_CODES; c += 256) {
        float p = (float)counts[c] * (1.0f / (float)N_VEC);
        h += p * logf(p + 1e-10f);
    }
    red[threadIdx.x] = h;
    __syncthreads();
    for (int s = 128; s; s >>= 1) {
        if (threadIdx.x < s) red[threadIdx.x] += red[threadIdx.x + s];
        __syncthreads();
    }
    if (threadIdx.x == 0) {
        out_scalars[0] = BETA * loss_acc[0] / (float)(N_VEC * DIM);
        out_scalars[1] = expf(-red[0]);
    }
}

extern "C" void kernel_launch(void* const* d_in, const int* in_sizes, int n_in,
                              void* d_out, int out_size, void* d_ws, size_t ws_size,
                              hipStream_t stream) {
    const float* x = (const float*)d_in[0];
    const float* emb = (const float*)d_in[1];

    float* out = (float*)d_out;
    float* out_q = out;                                   // N*DIM
    float* out_ind = out + (size_t)N_VEC * DIM;           // N
    float* out_scalars = out_ind + N_VEC;                 // 2

    // x hi/lo scratch lives in d_out's quantized region (rewritten by finish)
    ushort* xh = (ushort*)out;                            // 8 MB
    ushort* xl = xh + (size_t)N_VEC * DIM;                // 8 MB

    char* wp = (char*)d_ws;
    ushort* eh = (ushort*)wp;  wp += (size_t)M_CODES * DIM * 2;   // 4 MB
    ushort* el = (ushort*)wp;  wp += (size_t)M_CODES * DIM * 2;   // 4 MB
    float* e2 = (float*)wp;    wp += (size_t)M_CODES * 4;         // 32 KB
    unsigned long long* partials = (unsigned long long*)wp;
    wp += (size_t)NPART * N_VEC * 8;                              // 512 KB
    unsigned* counts = (unsigned*)wp; wp += (size_t)M_CODES * 4;  // 32 KB
    float* loss_acc = (float*)wp;                                 // 4 B

    prep_kernel<<<(N_VEC + M_CODES) / 4, 256, 0, stream>>>(x, emb, xh, xl, eh, el,
                                                           e2, counts, loss_acc);

    hipFuncSetAttribute((const void*)vq_mfma_kernel,
                        hipFuncAttributeMaxDynamicSharedMemorySize, LDS_TOTAL);
    vq_mfma_kernel<<<(N_VEC / BM) * NSLICE, 512, LDS_TOTAL, stream>>>(
        xh, xl, eh, el, e2, partials);

    finish_kernel<<<N_VEC / 4, 256, 0, stream>>>(x, emb, partials, out_ind, out_q,
                                                 counts, loss_acc);
    finalize_kernel<<<1, 256, 0, stream>>>(counts, loss_acc, out_scalars);
}